// Round 7
// baseline (125.772 us; speedup 1.0000x reference)
//
#include <hip/hip_runtime.h>
#include <hip/hip_bf16.h>

typedef __attribute__((ext_vector_type(4))) float f32x4;
typedef __attribute__((ext_vector_type(8))) short bf16x8;

static __device__ __forceinline__ unsigned short f2bf(float f) {
    union { float f; unsigned int u; } v; v.f = f;
    unsigned int u = v.u;
    u += 0x7fffu + ((u >> 16) & 1u);   // round-to-nearest-even
    return (unsigned short)(u >> 16);
}

// prep: permute adj and W into MFMA fragment-order bf16 (adj/W only — x is
// consumed directly by the fused kernel).
// Fragment chunk = 16 (m|n) x 32 (k) stored as [lane][8] bf16 (1 KB),
// lane = ((k&31)>>3)*16 + (m&15), elem = k&7.
//   afrag chunk = k0g*32 + m0   (k0g 0..15, m0 0..31; 512 chunks)
//   wfrag chunk = k0g*16 + n0   (Wt[n][k] = W[k][n]; k0g 0..7, n0 0..15; 128)
__global__ __launch_bounds__(256) void prep(
    const float* __restrict__ adj, const float* __restrict__ W,
    unsigned short* __restrict__ af, unsigned short* __restrict__ wf)
{
    const int wave = threadIdx.x >> 6, lane = threadIdx.x & 63;
    const int l15 = lane & 15, quad = lane >> 4;
    const int c = blockIdx.x * 4 + wave;     // 0..639, wave-uniform

    float t[8];
    unsigned short* dst;
    if (c < 512) {
        int k0g = c >> 5, m0 = c & 31;
        const float* src = adj + ((size_t)(m0 * 16 + l15)) * 512 + k0g * 32 + quad * 8;
        float4 f0 = *reinterpret_cast<const float4*>(src);
        float4 f1 = *reinterpret_cast<const float4*>(src + 4);
        t[0]=f0.x; t[1]=f0.y; t[2]=f0.z; t[3]=f0.w;
        t[4]=f1.x; t[5]=f1.y; t[6]=f1.z; t[7]=f1.w;
        dst = af + (size_t)c * 512 + lane * 8;
    } else {
        int c3 = c - 512, k0g = c3 >> 4, n0 = c3 & 15;
        int k = k0g * 32 + quad * 8, n = n0 * 16 + l15;
#pragma unroll
        for (int jj = 0; jj < 8; jj++) t[jj] = W[(size_t)(k + jj) * 256 + n];
        dst = wf + (size_t)c3 * 512 + lane * 8;
    }
    union { unsigned short u[8]; uint4 q; } o;
#pragma unroll
    for (int jj = 0; jj < 8; jj++) o.u[jj] = f2bf(t[jj]);
    *reinterpret_cast<uint4*>(dst) = o.q;
}

// Fused: block = (batch b, 32-col d-slice dq), 512 threads (8 waves).
// Each wave owns 64 rows in both phases -> acc = 32 regs/thread.
// Phase 1: h[j][32 d] = x_b @ W[:,slice]; x read DIRECTLY as fp32 (coalesced
//          128 B/row segments) + in-register cvt_pk to bf16; result -> LDS in
//          exact phase-2 B-fragment order.
// Phase 2: out_b[:, slice] = adj @ h.  No barriers inside K-loops.
__global__ __launch_bounds__(512, 4) void fused(
    const float* __restrict__ x,
    const unsigned short* __restrict__ wf,
    const unsigned short* __restrict__ af,
    float* __restrict__ out)
{
    // ht[k0g(16)][ni(2)][lane(64)][8] bf16 = 32 KiB
    __shared__ __align__(16) unsigned short ht[16384];

    const int tid  = threadIdx.x;
    const int lane = tid & 63, wave = tid >> 6;   // wave 0..7
    const int l15  = lane & 15, quad = lane >> 4;
    const int b    = blockIdx.x;   // 0..63 (fast -> same-batch blocks share an XCD)
    const int dq   = blockIdx.y;   // 0..7

    const float* xb = x + ((size_t)b * 512 + wave * 64) * 256;

    f32x4 acc[4][2];
#pragma unroll
    for (int mi = 0; mi < 4; mi++)
#pragma unroll
        for (int ni = 0; ni < 2; ni++) acc[mi][ni] = (f32x4){0.f,0.f,0.f,0.f};

    // ---------------- Phase 1: K=256, 8 k-steps; wave owns 64 j-rows ----------------
#pragma unroll 2
    for (int k0g = 0; k0g < 8; k0g++) {
        bf16x8 bw[2];
#pragma unroll
        for (int ni = 0; ni < 2; ni++)
            bw[ni] = *reinterpret_cast<const bf16x8*>(
                wf + ((size_t)((k0g * 16 + dq * 2 + ni) * 64) + lane) * 8);
#pragma unroll
        for (int mi = 0; mi < 4; mi++) {
            const float* px = xb + (size_t)(mi * 16 + l15) * 256 + k0g * 32 + quad * 8;
            float4 v0 = *reinterpret_cast<const float4*>(px);
            float4 v1 = *reinterpret_cast<const float4*>(px + 4);
            union { __hip_bfloat162 h[4]; bf16x8 v; } a;
            a.h[0] = __float22bfloat162_rn(make_float2(v0.x, v0.y));
            a.h[1] = __float22bfloat162_rn(make_float2(v0.z, v0.w));
            a.h[2] = __float22bfloat162_rn(make_float2(v1.x, v1.y));
            a.h[3] = __float22bfloat162_rn(make_float2(v1.z, v1.w));
#pragma unroll
            for (int ni = 0; ni < 2; ni++)
                acc[mi][ni] = __builtin_amdgcn_mfma_f32_16x16x32_bf16(
                    a.v, bw[ni], acc[mi][ni], 0, 0, 0);
        }
    }

    // Epilogue: C-layout (j = wave*64 + mi*16 + quad*4 + r, dl = ni*16 + l15) ->
    // B-frag storage: k0g2 = wave*2 + (mi>>1), lane' = ((mi&1)*2+(quad>>1))*16 + l15,
    // elem = (quad&1)*4 + r  (r contiguous -> 8 B ds_write, conflict-free).
#pragma unroll
    for (int mi = 0; mi < 4; mi++) {
        int k0g2  = wave * 2 + (mi >> 1);
        int quadp = (mi & 1) * 2 + (quad >> 1);
#pragma unroll
        for (int ni = 0; ni < 2; ni++) {
            ushort4 p;
            p.x = f2bf(acc[mi][ni][0]); p.y = f2bf(acc[mi][ni][1]);
            p.z = f2bf(acc[mi][ni][2]); p.w = f2bf(acc[mi][ni][3]);
            *reinterpret_cast<ushort4*>(
                ht + ((k0g2 * 2 + ni) * 64 + quadp * 16 + l15) * 8
                   + (quad & 1) * 4) = p;
        }
    }
    __syncthreads();

    // ---------------- Phase 2: K=512, 16 k-steps; wave owns 64 out-rows ----------------
    f32x4 o[4][2];
#pragma unroll
    for (int mi = 0; mi < 4; mi++)
#pragma unroll
        for (int ni = 0; ni < 2; ni++) o[mi][ni] = (f32x4){0.f,0.f,0.f,0.f};

#pragma unroll 2
    for (int k0g = 0; k0g < 16; k0g++) {
        bf16x8 a2[4];
#pragma unroll
        for (int mi = 0; mi < 4; mi++)
            a2[mi] = *reinterpret_cast<const bf16x8*>(
                af + ((size_t)((k0g * 32 + wave * 4 + mi) * 64) + lane) * 8);
        bf16x8 hb[2];
#pragma unroll
        for (int ni = 0; ni < 2; ni++)
            hb[ni] = *reinterpret_cast<const bf16x8*>(
                ht + ((k0g * 2 + ni) * 64 + lane) * 8);
#pragma unroll
        for (int mi = 0; mi < 4; mi++)
#pragma unroll
            for (int ni = 0; ni < 2; ni++)
                o[mi][ni] = __builtin_amdgcn_mfma_f32_16x16x32_bf16(
                    a2[mi], hb[ni], o[mi][ni], 0, 0, 0);
    }

    // Store out fp32: row i = wave*64 + mi*16 + quad*4 + r, col dq*32 + ni*16 + l15
    float* ob = out + ((size_t)b * 512) * 256 + dq * 32;
#pragma unroll
    for (int mi = 0; mi < 4; mi++) {
        int i0 = wave * 64 + mi * 16 + quad * 4;
#pragma unroll
        for (int ni = 0; ni < 2; ni++) {
            int d = ni * 16 + l15;
#pragma unroll
            for (int r = 0; r < 4; r++)
                ob[(size_t)(i0 + r) * 256 + d] = o[mi][ni][r];
        }
    }
}

extern "C" void kernel_launch(void* const* d_in, const int* in_sizes, int n_in,
                              void* d_out, int out_size, void* d_ws, size_t ws_size,
                              hipStream_t stream) {
    const float* x   = (const float*)d_in[0];
    // d_in[1] = batch ids (unused; block-contiguous layout by construction)
    const float* W   = (const float*)d_in[2];
    const float* Adj = (const float*)d_in[3];
    float* out = (float*)d_out;

    unsigned short* afrag = (unsigned short*)d_ws;   // 262144 elems (512 KB)
    unsigned short* wfrag = afrag + 262144;          // 65536 elems  (128 KB)

    prep<<<160, 256, 0, stream>>>(Adj, W, afrag, wfrag);
    fused<<<dim3(64, 8), 512, 0, stream>>>(x, wfrag, afrag, out);
}

// Round 8
// 109.818 us; speedup vs baseline: 1.1453x; 1.1453x over previous
//
#include <hip/hip_runtime.h>

typedef __attribute__((ext_vector_type(4))) float f32x4;
typedef __attribute__((ext_vector_type(8))) short bf16x8;

static __device__ __forceinline__ unsigned short f2bf(float f) {
    union { float f; unsigned int u; } v; v.f = f;
    unsigned int u = v.u;
    u += 0x7fffu + ((u >> 16) & 1u);   // round-to-nearest-even
    return (unsigned short)(u >> 16);
}

// prep: permute inputs into MFMA fragment-order bf16 buffers.
// Fragment chunk = 16 (m|n) x 32 (k) tile stored as [lane][8] bf16 (1 KB),
// lane = ((k&31)>>3)*16 + (m&15), elem jj = k&7.
//   xfrag  chunk = (b*8 + k0g)*32 + m0          (16384 chunks)
//   adjfrag chunk = k0g*32 + m0                 (512 chunks)
//   wtfrag chunk = k0g*16 + n0   (Wt[n][k]=W[k][n], 128 chunks)
__global__ __launch_bounds__(256) void prep(
    const float* __restrict__ x, const float* __restrict__ adj,
    const float* __restrict__ W,
    unsigned short* __restrict__ xf, unsigned short* __restrict__ af,
    unsigned short* __restrict__ wf)
{
    const int wave = threadIdx.x >> 6, lane = threadIdx.x & 63;
    const int l15 = lane & 15, quad = lane >> 4;
    const int c = blockIdx.x * 4 + wave;     // 0..17023, wave-uniform

    float t[8];
    unsigned short* dst;
    if (c < 16384) {
        int b = c >> 8, k0g = (c >> 5) & 7, m0 = c & 31;
        const float* src = x + ((size_t)(b * 512 + m0 * 16 + l15)) * 256 + k0g * 32 + quad * 8;
        float4 f0 = *reinterpret_cast<const float4*>(src);
        float4 f1 = *reinterpret_cast<const float4*>(src + 4);
        t[0]=f0.x; t[1]=f0.y; t[2]=f0.z; t[3]=f0.w;
        t[4]=f1.x; t[5]=f1.y; t[6]=f1.z; t[7]=f1.w;
        dst = xf + (size_t)c * 512 + lane * 8;
    } else if (c < 16896) {
        int c2 = c - 16384, k0g = c2 >> 5, m0 = c2 & 31;
        const float* src = adj + ((size_t)(m0 * 16 + l15)) * 512 + k0g * 32 + quad * 8;
        float4 f0 = *reinterpret_cast<const float4*>(src);
        float4 f1 = *reinterpret_cast<const float4*>(src + 4);
        t[0]=f0.x; t[1]=f0.y; t[2]=f0.z; t[3]=f0.w;
        t[4]=f1.x; t[5]=f1.y; t[6]=f1.z; t[7]=f1.w;
        dst = af + (size_t)c2 * 512 + lane * 8;
    } else {
        int c3 = c - 16896, k0g = c3 >> 4, n0 = c3 & 15;
        int k = k0g * 32 + quad * 8, n = n0 * 16 + l15;
#pragma unroll
        for (int jj = 0; jj < 8; jj++) t[jj] = W[(size_t)(k + jj) * 256 + n];
        dst = wf + (size_t)c3 * 512 + lane * 8;
    }
    union { unsigned short u[8]; uint4 q; } o;
#pragma unroll
    for (int jj = 0; jj < 8; jj++) o.u[jj] = f2bf(t[jj]);
    *reinterpret_cast<uint4*>(dst) = o.q;
}

// Fused: block = (batch b, 32-col d-slice dq), 512 threads (8 waves).
// Both K-loops are fully unrolled with rotating register buffers so loads for
// step k+2 are issued before step k's MFMAs (software pipeline; no in-loop
// barriers anywhere).
__global__ __launch_bounds__(512, 2) void fused(
    const unsigned short* __restrict__ xf,
    const unsigned short* __restrict__ wf,
    const unsigned short* __restrict__ af,
    float* __restrict__ out)
{
    // ht[k0g(16)][ni(2)][lane(64)][8] bf16 = 32 KiB
    __shared__ __align__(16) unsigned short ht[16384];

    const int tid  = threadIdx.x;
    const int lane = tid & 63, wave = tid >> 6;   // wave 0..7
    const int l15  = lane & 15, quad = lane >> 4;
    const int b    = blockIdx.x;   // 0..63 (fast -> same-batch blocks share an XCD)
    const int dq   = blockIdx.y;   // 0..7

    // Per-lane base pointers (element units). Strides:
    //   xf: k0g step 32*64*8 = 16384 elems, mi step 512 elems
    //   wf: k0g step 16*64*8 =  8192 elems, ni step 512 elems
    //   af: k0g step 32*64*8 = 16384 elems, mi step 512 elems
    const unsigned short* xfp = xf + ((size_t)(b * 8) * 32 + wave * 4) * 512 + lane * 8;
    const unsigned short* wfp = wf + ((size_t)(dq * 2)) * 512 + lane * 8;
    const unsigned short* afp = af + ((size_t)(wave * 4)) * 512 + lane * 8;

    // ---------------- Phase 1: K=256, 8 k-steps; wave owns 64 j-rows ----------------
    f32x4 acc[4][2];
#pragma unroll
    for (int mi = 0; mi < 4; mi++)
#pragma unroll
        for (int ni = 0; ni < 2; ni++) acc[mi][ni] = (f32x4){0.f,0.f,0.f,0.f};

    bf16x8 aP[3][4], bP[3][2];
#define P1LOAD(K, S)                                                              \
    do {                                                                          \
        _Pragma("unroll")                                                         \
        for (int mi = 0; mi < 4; mi++)                                            \
            aP[S][mi] = *reinterpret_cast<const bf16x8*>(                         \
                xfp + (size_t)(K) * 16384 + mi * 512);                            \
        _Pragma("unroll")                                                         \
        for (int ni = 0; ni < 2; ni++)                                            \
            bP[S][ni] = *reinterpret_cast<const bf16x8*>(                         \
                wfp + (size_t)(K) * 8192 + ni * 512);                             \
    } while (0)

    P1LOAD(0, 0);
    P1LOAD(1, 1);
#pragma unroll
    for (int k = 0; k < 8; k++) {
        if (k + 2 < 8) {
            const int s2 = (k + 2) % 3;
            P1LOAD(k + 2, s2);
        }
        const int s = k % 3;
#pragma unroll
        for (int mi = 0; mi < 4; mi++)
#pragma unroll
            for (int ni = 0; ni < 2; ni++)
                acc[mi][ni] = __builtin_amdgcn_mfma_f32_16x16x32_bf16(
                    aP[s][mi], bP[s][ni], acc[mi][ni], 0, 0, 0);
    }
#undef P1LOAD

    // Epilogue: C-layout (j = wave*64 + mi*16 + quad*4 + r, dl = ni*16 + l15) ->
    // B-frag storage: k0g2 = wave*2 + (mi>>1), lane' = ((mi&1)*2+(quad>>1))*16 + l15,
    // elem = (quad&1)*4 + r  (r contiguous -> 8 B ds_write, conflict-free).
#pragma unroll
    for (int mi = 0; mi < 4; mi++) {
        int k0g2  = wave * 2 + (mi >> 1);
        int quadp = (mi & 1) * 2 + (quad >> 1);
#pragma unroll
        for (int ni = 0; ni < 2; ni++) {
            ushort4 p;
            p.x = f2bf(acc[mi][ni][0]); p.y = f2bf(acc[mi][ni][1]);
            p.z = f2bf(acc[mi][ni][2]); p.w = f2bf(acc[mi][ni][3]);
            *reinterpret_cast<ushort4*>(
                ht + ((k0g2 * 2 + ni) * 64 + quadp * 16 + l15) * 8
                   + (quad & 1) * 4) = p;
        }
    }
    __syncthreads();

    // ---------------- Phase 2: K=512, 16 k-steps; wave owns 64 out-rows ----------------
    f32x4 o[4][2];
#pragma unroll
    for (int mi = 0; mi < 4; mi++)
#pragma unroll
        for (int ni = 0; ni < 2; ni++) o[mi][ni] = (f32x4){0.f,0.f,0.f,0.f};

    bf16x8 A2[3][4], Hb[2][2];
#define P2LOADA(K, S)                                                             \
    do {                                                                          \
        _Pragma("unroll")                                                         \
        for (int mi = 0; mi < 4; mi++)                                            \
            A2[S][mi] = *reinterpret_cast<const bf16x8*>(                         \
                afp + (size_t)(K) * 16384 + mi * 512);                            \
    } while (0)
#define P2LOADH(K, S)                                                             \
    do {                                                                          \
        _Pragma("unroll")                                                         \
        for (int ni = 0; ni < 2; ni++)                                            \
            Hb[S][ni] = *reinterpret_cast<const bf16x8*>(                         \
                ht + ((K) * 2 + ni) * 512 + lane * 8);                            \
    } while (0)

    P2LOADA(0, 0);
    P2LOADA(1, 1);
    P2LOADH(0, 0);
#pragma unroll
    for (int k = 0; k < 16; k++) {
        if (k + 2 < 16) {
            const int s2 = (k + 2) % 3;
            P2LOADA(k + 2, s2);
        }
        if (k + 1 < 16) {
            const int sh2 = (k + 1) & 1;
            P2LOADH(k + 1, sh2);
        }
        const int s = k % 3, sh = k & 1;
#pragma unroll
        for (int mi = 0; mi < 4; mi++)
#pragma unroll
            for (int ni = 0; ni < 2; ni++)
                o[mi][ni] = __builtin_amdgcn_mfma_f32_16x16x32_bf16(
                    A2[s][mi], Hb[sh][ni], o[mi][ni], 0, 0, 0);
    }
#undef P2LOADA
#undef P2LOADH

    // Store out fp32: row i = wave*64 + mi*16 + quad*4 + r, col dq*32 + ni*16 + l15
    float* ob = out + ((size_t)b * 512) * 256 + dq * 32;
#pragma unroll
    for (int mi = 0; mi < 4; mi++) {
        int i0 = wave * 64 + mi * 16 + quad * 4;
#pragma unroll
        for (int ni = 0; ni < 2; ni++) {
            int d = ni * 16 + l15;
#pragma unroll
            for (int r = 0; r < 4; r++)
                ob[(size_t)(i0 + r) * 256 + d] = o[mi][ni][r];
        }
    }
}

extern "C" void kernel_launch(void* const* d_in, const int* in_sizes, int n_in,
                              void* d_out, int out_size, void* d_ws, size_t ws_size,
                              hipStream_t stream) {
    const float* x   = (const float*)d_in[0];
    // d_in[1] = batch ids (unused; block-contiguous layout by construction)
    const float* W   = (const float*)d_in[2];
    const float* Adj = (const float*)d_in[3];
    float* out = (float*)d_out;

    unsigned short* xfrag = (unsigned short*)d_ws;    // 8388608 elems (16 MB)
    unsigned short* afrag = xfrag + 8388608;          // 262144 elems (512 KB)
    unsigned short* wfrag = afrag + 262144;           // 65536 elems (128 KB)

    prep<<<4256, 256, 0, stream>>>(x, Adj, W, xfrag, afrag, wfrag);
    fused<<<dim3(64, 8), 512, 0, stream>>>(xfrag, wfrag, afrag, out);
}

// Round 9
// 104.158 us; speedup vs baseline: 1.2075x; 1.0543x over previous
//
#include <hip/hip_runtime.h>

typedef __attribute__((ext_vector_type(4))) float f32x4;
typedef __attribute__((ext_vector_type(8))) short bf16x8;

static __device__ __forceinline__ unsigned short f2bf(float f) {
    union { float f; unsigned int u; } v; v.f = f;
    unsigned int u = v.u;
    u += 0x7fffu + ((u >> 16) & 1u);   // round-to-nearest-even
    return (unsigned short)(u >> 16);
}

// prep: permute inputs into MFMA fragment-order bf16 buffers.
// Fragment chunk = 16 (m|n) x 32 (k) tile stored as [lane][8] bf16 (1 KB),
// lane = ((k&31)>>3)*16 + (m&15), elem jj = k&7.
//   xfrag  chunk = (b*8 + k0g)*32 + m0          (16384 chunks)
//   adjfrag chunk = k0g*32 + m0                 (512 chunks)
//   wtfrag chunk = k0g*16 + n0   (Wt[n][k]=W[k][n], 128 chunks)
__global__ __launch_bounds__(256) void prep(
    const float* __restrict__ x, const float* __restrict__ adj,
    const float* __restrict__ W,
    unsigned short* __restrict__ xf, unsigned short* __restrict__ af,
    unsigned short* __restrict__ wf)
{
    const int wave = threadIdx.x >> 6, lane = threadIdx.x & 63;
    const int l15 = lane & 15, quad = lane >> 4;
    const int c = blockIdx.x * 4 + wave;     // 0..17023, wave-uniform

    float t[8];
    unsigned short* dst;
    if (c < 16384) {
        int b = c >> 8, k0g = (c >> 5) & 7, m0 = c & 31;
        const float* src = x + ((size_t)(b * 512 + m0 * 16 + l15)) * 256 + k0g * 32 + quad * 8;
        float4 f0 = *reinterpret_cast<const float4*>(src);
        float4 f1 = *reinterpret_cast<const float4*>(src + 4);
        t[0]=f0.x; t[1]=f0.y; t[2]=f0.z; t[3]=f0.w;
        t[4]=f1.x; t[5]=f1.y; t[6]=f1.z; t[7]=f1.w;
        dst = xf + (size_t)c * 512 + lane * 8;
    } else if (c < 16896) {
        int c2 = c - 16384, k0g = c2 >> 5, m0 = c2 & 31;
        const float* src = adj + ((size_t)(m0 * 16 + l15)) * 512 + k0g * 32 + quad * 8;
        float4 f0 = *reinterpret_cast<const float4*>(src);
        float4 f1 = *reinterpret_cast<const float4*>(src + 4);
        t[0]=f0.x; t[1]=f0.y; t[2]=f0.z; t[3]=f0.w;
        t[4]=f1.x; t[5]=f1.y; t[6]=f1.z; t[7]=f1.w;
        dst = af + (size_t)c2 * 512 + lane * 8;
    } else {
        int c3 = c - 16896, k0g = c3 >> 4, n0 = c3 & 15;
        int k = k0g * 32 + quad * 8, n = n0 * 16 + l15;
#pragma unroll
        for (int jj = 0; jj < 8; jj++) t[jj] = W[(size_t)(k + jj) * 256 + n];
        dst = wf + (size_t)c3 * 512 + lane * 8;
    }
    union { unsigned short u[8]; uint4 q; } o;
#pragma unroll
    for (int jj = 0; jj < 8; jj++) o.u[jj] = f2bf(t[jj]);
    *reinterpret_cast<uint4*>(dst) = o.q;
}

// Fused: block = (batch b, 64-col d-slice dq), 512 threads (8 waves).
// Each wave owns 64 rows x 64 cols -> 4x4 MFMA tile, 16 MFMA per 8 global
// loads per k-step (2x the MFMA:load ratio of the 32-wide variant).
// Phase 1: h[j][64 d] = x_b @ W[:,slice] -> LDS (exact phase-2 B-frag order).
// Phase 2: out_b[:, slice] = adj @ h.  No barriers inside K-loops.
__global__ __launch_bounds__(512, 2) void fused(
    const unsigned short* __restrict__ xf,
    const unsigned short* __restrict__ wf,
    const unsigned short* __restrict__ af,
    float* __restrict__ out)
{
    // ht[k0g(16)][ni(4)][lane(64)][8] bf16 = 64 KiB
    __shared__ __align__(16) unsigned short ht[32768];

    const int tid  = threadIdx.x;
    const int lane = tid & 63, wave = tid >> 6;   // wave 0..7
    const int l15  = lane & 15, quad = lane >> 4;
    const int b    = blockIdx.x;   // 0..63 (fast -> same-batch blocks share an XCD)
    const int dq   = blockIdx.y;   // 0..3

    // Per-lane base pointers (element units). Strides:
    //   xf: k0g step 32*64*8 = 16384 elems, mi step 512 elems
    //   wf: k0g step 16*64*8 =  8192 elems, ni step 512 elems
    //   af: k0g step 32*64*8 = 16384 elems, mi step 512 elems
    const unsigned short* xfp = xf + ((size_t)(b * 8) * 32 + wave * 4) * 512 + lane * 8;
    const unsigned short* wfp = wf + ((size_t)(dq * 4)) * 512 + lane * 8;
    const unsigned short* afp = af + ((size_t)(wave * 4)) * 512 + lane * 8;

    // ---------------- Phase 1: K=256, 8 k-steps; wave owns 64 j-rows ----------------
    f32x4 acc[4][4];
#pragma unroll
    for (int mi = 0; mi < 4; mi++)
#pragma unroll
        for (int ni = 0; ni < 4; ni++) acc[mi][ni] = (f32x4){0.f,0.f,0.f,0.f};

#pragma unroll
    for (int k = 0; k < 8; k++) {
        bf16x8 bw[4], a[4];
#pragma unroll
        for (int ni = 0; ni < 4; ni++)
            bw[ni] = *reinterpret_cast<const bf16x8*>(
                wfp + (size_t)k * 8192 + ni * 512);
#pragma unroll
        for (int mi = 0; mi < 4; mi++)
            a[mi] = *reinterpret_cast<const bf16x8*>(
                xfp + (size_t)k * 16384 + mi * 512);
#pragma unroll
        for (int mi = 0; mi < 4; mi++)
#pragma unroll
            for (int ni = 0; ni < 4; ni++)
                acc[mi][ni] = __builtin_amdgcn_mfma_f32_16x16x32_bf16(
                    a[mi], bw[ni], acc[mi][ni], 0, 0, 0);
    }

    // Epilogue: C-layout (j = wave*64 + mi*16 + quad*4 + r, dl = ni*16 + l15) ->
    // B-frag storage: k0g2 = wave*2 + (mi>>1), lane' = ((mi&1)*2+(quad>>1))*16 + l15,
    // elem = (quad&1)*4 + r  (r contiguous -> 8 B ds_write, conflict-free).
#pragma unroll
    for (int mi = 0; mi < 4; mi++) {
        int k0g2  = wave * 2 + (mi >> 1);
        int quadp = (mi & 1) * 2 + (quad >> 1);
#pragma unroll
        for (int ni = 0; ni < 4; ni++) {
            ushort4 p;
            p.x = f2bf(acc[mi][ni][0]); p.y = f2bf(acc[mi][ni][1]);
            p.z = f2bf(acc[mi][ni][2]); p.w = f2bf(acc[mi][ni][3]);
            *reinterpret_cast<ushort4*>(
                ht + ((k0g2 * 4 + ni) * 64 + quadp * 16 + l15) * 8
                   + (quad & 1) * 4) = p;
        }
    }
    __syncthreads();

    // ---------------- Phase 2: K=512, 16 k-steps; wave owns 64 out-rows ----------------
    f32x4 o[4][4];
#pragma unroll
    for (int mi = 0; mi < 4; mi++)
#pragma unroll
        for (int ni = 0; ni < 4; ni++) o[mi][ni] = (f32x4){0.f,0.f,0.f,0.f};

#pragma unroll
    for (int k = 0; k < 16; k++) {
        bf16x8 a2[4], hb[4];
#pragma unroll
        for (int mi = 0; mi < 4; mi++)
            a2[mi] = *reinterpret_cast<const bf16x8*>(
                afp + (size_t)k * 16384 + mi * 512);
#pragma unroll
        for (int ni = 0; ni < 4; ni++)
            hb[ni] = *reinterpret_cast<const bf16x8*>(
                ht + ((k * 4 + ni) * 64 + lane) * 8);
#pragma unroll
        for (int mi = 0; mi < 4; mi++)
#pragma unroll
            for (int ni = 0; ni < 4; ni++)
                o[mi][ni] = __builtin_amdgcn_mfma_f32_16x16x32_bf16(
                    a2[mi], hb[ni], o[mi][ni], 0, 0, 0);
    }

    // Store out fp32: row i = wave*64 + mi*16 + quad*4 + r, col dq*64 + ni*16 + l15
    float* ob = out + ((size_t)b * 512) * 256 + dq * 64;
#pragma unroll
    for (int mi = 0; mi < 4; mi++) {
        int i0 = wave * 64 + mi * 16 + quad * 4;
#pragma unroll
        for (int ni = 0; ni < 4; ni++) {
            int d = ni * 16 + l15;
#pragma unroll
            for (int r = 0; r < 4; r++)
                ob[(size_t)(i0 + r) * 256 + d] = o[mi][ni][r];
        }
    }
}

extern "C" void kernel_launch(void* const* d_in, const int* in_sizes, int n_in,
                              void* d_out, int out_size, void* d_ws, size_t ws_size,
                              hipStream_t stream) {
    const float* x   = (const float*)d_in[0];
    // d_in[1] = batch ids (unused; block-contiguous layout by construction)
    const float* W   = (const float*)d_in[2];
    const float* Adj = (const float*)d_in[3];
    float* out = (float*)d_out;

    unsigned short* xfrag = (unsigned short*)d_ws;    // 8388608 elems (16 MB)
    unsigned short* afrag = xfrag + 8388608;          // 262144 elems (512 KB)
    unsigned short* wfrag = afrag + 262144;           // 65536 elems (128 KB)

    prep<<<4256, 256, 0, stream>>>(x, Adj, W, xfrag, afrag, wfrag);
    fused<<<dim3(64, 4), 512, 0, stream>>>(xfrag, wfrag, afrag, out);
}